// Round 4
// baseline (415.328 us; speedup 1.0000x reference)
//
#include <hip/hip_runtime.h>

#define N_NODES 100000
#define N_EDGES 1600000
#define DIM     128
#define OUTD    16
#define SCAN_CHUNK 1024
#define NB ((N_NODES + SCAN_CHUNK - 1) / SCAN_CHUNK)   // 98

typedef unsigned int  uint;
typedef unsigned short ushort;
typedef __attribute__((ext_vector_type(8))) short short8;   // 8 bf16 (4 VGPRs)
typedef __attribute__((ext_vector_type(4))) float f32x4;    // MFMA C/D

__device__ __forceinline__ ushort f2bf(float f) {           // RNE fp32->bf16
    uint u = __float_as_uint(f);
    u = u + 0x7fffu + ((u >> 16) & 1u);
    return (ushort)(u >> 16);
}
__device__ __forceinline__ float bflo(uint v) { return __uint_as_float(v << 16); }
__device__ __forceinline__ float bfhi(uint v) { return __uint_as_float(v & 0xffff0000u); }

#define SLICES 8
#define RPS (N_NODES / SLICES)   // 12500 rows/slice -> 50 KB window per XCD L2
#define SBPS 224                 // blocks per slice

// ---------------- degree count, destination-sliced (atomics stay in one XCD L2) ----
__global__ __launch_bounds__(256) void k_count(const int* __restrict__ row,
                                               int* __restrict__ deg) {
    int slice = blockIdx.x % SLICES;
    int bi    = blockIdx.x / SLICES;
    int lo = slice * RPS, hi = lo + RPS;
    int stride = SBPS * 256;
    for (int e = bi * 256 + threadIdx.x; e < N_EDGES; e += stride) {
        int r = row[e];
        if (r >= lo && r < hi) atomicAdd(&deg[r], 1);
    }
}

// ---------------- pure streaming conversions: x->bf16, W transposes ----------------
__global__ __launch_bounds__(256) void k_convert(
        const float4* __restrict__ x4,
        const float* __restrict__ We, const float* __restrict__ W1,
        const float* __restrict__ W2, const float* __restrict__ Wc,
        ushort* __restrict__ xb, ushort* __restrict__ Wt, ushort* __restrict__ Wct) {
    int tid = blockIdx.x * blockDim.x + threadIdx.x;
    int stride = gridDim.x * blockDim.x;
    for (int i = tid; i < N_NODES * DIM / 4; i += stride) {
        float4 v = x4[i];
        ushort4 r;
        r.x = f2bf(v.x); r.y = f2bf(v.y); r.z = f2bf(v.z); r.w = f2bf(v.w);
        *(ushort4*)(xb + (size_t)i * 4) = r;
    }
    for (int i = tid; i < 3 * DIM * DIM; i += stride) {   // Wt[br][n][k] = W[br][k][n]
        int b = i >> 14, r2 = i & (DIM * DIM - 1);
        int k = r2 >> 7, n = r2 & 127;
        const float* W = (b == 0) ? We : (b == 1) ? W1 : W2;
        Wt[b * DIM * DIM + n * DIM + k] = f2bf(W[r2]);
    }
    for (int i = tid; i < 384 * OUTD; i += stride) {      // Wct[o][k] = Wc[k][o]
        int k = i >> 4, o = i & 15;
        Wct[o * 384 + k] = f2bf(Wc[i]);
    }
}

// ---------------- scans (build CSR offsets) ----------------
__global__ void k_scan1(const int* __restrict__ deg, int* __restrict__ bsum) {
    __shared__ int sd[256];
    int t = threadIdx.x;
    int base = blockIdx.x * SCAN_CHUNK + t * 4;
    int s = 0;
#pragma unroll
    for (int j = 0; j < 4; ++j) { int i = base + j; if (i < N_NODES) s += deg[i]; }
    sd[t] = s;
    __syncthreads();
    for (int off = 128; off > 0; off >>= 1) {
        if (t < off) sd[t] += sd[t + off];
        __syncthreads();
    }
    if (t == 0) bsum[blockIdx.x] = sd[0];
}

__global__ void k_scan2(const int* __restrict__ bsum, int* __restrict__ boff,
                        int* __restrict__ offsets) {
    __shared__ int s[128];
    int t = threadIdx.x;
    int v = (t < NB) ? bsum[t] : 0;
    s[t] = v;
    __syncthreads();
    for (int off = 1; off < 128; off <<= 1) {
        int a = (t >= off) ? s[t - off] : 0;
        __syncthreads();
        s[t] += a;
        __syncthreads();
    }
    if (t < NB) boff[t] = s[t] - v;
    if (t == NB - 1) offsets[N_NODES] = s[t];
}

__global__ void k_scan3(const int* __restrict__ deg, const int* __restrict__ boff,
                        int* __restrict__ offsets, int* __restrict__ cursor) {
    __shared__ int sd[256];
    int t = threadIdx.x;
    int base = blockIdx.x * SCAN_CHUNK + t * 4;
    int d[4];
    int s = 0;
#pragma unroll
    for (int j = 0; j < 4; ++j) {
        int i = base + j;
        d[j] = (i < N_NODES) ? deg[i] : 0;
        s += d[j];
    }
    sd[t] = s;
    __syncthreads();
    for (int off = 1; off < 256; off <<= 1) {
        int add = (t >= off) ? sd[t - off] : 0;
        __syncthreads();
        sd[t] += add;
        __syncthreads();
    }
    int run = boff[blockIdx.x] + (sd[t] - s);
#pragma unroll
    for (int j = 0; j < 4; ++j) {
        int i = base + j;
        if (i < N_NODES) { offsets[i] = run; cursor[i] = run; run += d[j]; }
    }
}

// ---------------- scatter, destination-sliced ----------------
__global__ __launch_bounds__(256) void k_scatter(const int* __restrict__ row,
                                                 const int* __restrict__ col,
                                                 int* __restrict__ cursor,
                                                 int* __restrict__ csr_col) {
    int slice = blockIdx.x % SLICES;
    int bi    = blockIdx.x / SLICES;
    int lo = slice * RPS, hi = lo + RPS;
    int stride = SBPS * 256;
    for (int e = bi * 256 + threadIdx.x; e < N_EDGES; e += stride) {
        int r = row[e];
        int c = col[e];
        if (r >= lo && r < hi) {
            int p = atomicAdd(&cursor[r], 1);
            csr_col[p] = c;
        }
    }
}

// ---------------- SpMM: raw sums only (norm folded into k_fused epilogue) ----------
__global__ __launch_bounds__(256) void k_spmm(const ushort* __restrict__ in,
                                              ushort* __restrict__ outp,
                                              const int* __restrict__ offsets,
                                              const int* __restrict__ csr_col) {
    int wid = threadIdx.x >> 6, lane = threadIdx.x & 63;
    int node = blockIdx.x * 4 + wid;
    int start = __builtin_amdgcn_readfirstlane(offsets[node]);
    int end   = __builtin_amdgcn_readfirstlane(offsets[node + 1]);
    float a0 = 0.f, a1 = 0.f, b0 = 0.f, b1 = 0.f;
    int j = start;
    for (; j + 8 <= end; j += 8) {
        int c0 = csr_col[j + 0], c1 = csr_col[j + 1];
        int c2 = csr_col[j + 2], c3 = csr_col[j + 3];
        int c4 = csr_col[j + 4], c5 = csr_col[j + 5];
        int c6 = csr_col[j + 6], c7 = csr_col[j + 7];
        uint v0 = *(const uint*)(in + ((size_t)c0 << 7) + lane * 2);
        uint v1 = *(const uint*)(in + ((size_t)c1 << 7) + lane * 2);
        uint v2 = *(const uint*)(in + ((size_t)c2 << 7) + lane * 2);
        uint v3 = *(const uint*)(in + ((size_t)c3 << 7) + lane * 2);
        uint v4 = *(const uint*)(in + ((size_t)c4 << 7) + lane * 2);
        uint v5 = *(const uint*)(in + ((size_t)c5 << 7) + lane * 2);
        uint v6 = *(const uint*)(in + ((size_t)c6 << 7) + lane * 2);
        uint v7 = *(const uint*)(in + ((size_t)c7 << 7) + lane * 2);
        a0 += bflo(v0) + bflo(v1) + bflo(v2) + bflo(v3);
        a1 += bfhi(v0) + bfhi(v1) + bfhi(v2) + bfhi(v3);
        b0 += bflo(v4) + bflo(v5) + bflo(v6) + bflo(v7);
        b1 += bfhi(v4) + bfhi(v5) + bfhi(v6) + bfhi(v7);
    }
    for (; j < end; ++j) {
        int c = csr_col[j];
        uint v = *(const uint*)(in + ((size_t)c << 7) + lane * 2);
        a0 += bflo(v);
        a1 += bfhi(v);
    }
    a0 += b0; a1 += b1;
    uint o = (uint)f2bf(a0) | ((uint)f2bf(a1) << 16);
    *(uint*)(outp + ((size_t)node << 7) + lane * 2) = o;
}

// ---------------- fused MFMA GEMM x3 (+row-scale norm) + relu + classifier ---------
#define XSS (DIM + 8)   // 136 bf16 = 272B row stride

__global__ __launch_bounds__(256) void k_fused(
        const ushort* __restrict__ xb, const ushort* __restrict__ y1r,
        const ushort* __restrict__ y2r, const int* __restrict__ deg,
        const ushort* __restrict__ Wt, const ushort* __restrict__ Wct,
        const float* __restrict__ b_ego, const float* __restrict__ b_h1,
        const float* __restrict__ b_h2, const float* __restrict__ b_cls,
        float* __restrict__ out) {
    __shared__ __align__(16) ushort Xs[32 * XSS];
    __shared__ __align__(16) ushort Hs[32 * XSS];

    int t = threadIdx.x;
    int lane = t & 63, w = t >> 6;
    int q = lane >> 4, l = lane & 15;
    int node0 = blockIdx.x * 32;

    // per-thread dinv for the 8 C-rows this lane owns (rows mt*16 + q*4 + r)
    float dvv[2][4];
#pragma unroll
    for (int mt = 0; mt < 2; ++mt) {
        int4 dg = *(const int4*)(deg + node0 + mt * 16 + q * 4);
        dvv[mt][0] = 1.f / (float)max(dg.x, 1);
        dvv[mt][1] = 1.f / (float)max(dg.y, 1);
        dvv[mt][2] = 1.f / (float)max(dg.z, 1);
        dvv[mt][3] = 1.f / (float)max(dg.w, 1);
    }

    f32x4 cout0 = {0.f, 0.f, 0.f, 0.f}, cout1 = {0.f, 0.f, 0.f, 0.f};

    for (int br = 0; br < 3; ++br) {
        const ushort* src = (br == 0) ? xb : (br == 1) ? y1r : y2r;
        const ushort* Wtb = Wt + br * DIM * DIM;
        const float* bias = (br == 0) ? b_ego : (br == 1) ? b_h1 : b_h2;

        __syncthreads();
        {   // stage 32x128 bf16 tile (pure copy)
            int row = t >> 3, col = (t & 7) * 16;
            const ushort* sp = src + ((size_t)(node0 + row) << 7) + col;
            uint4 u0 = *(const uint4*)sp;
            uint4 u1 = *(const uint4*)(sp + 8);
            *(uint4*)(Xs + row * XSS + col) = u0;
            *(uint4*)(Xs + row * XSS + col + 8) = u1;
        }
        __syncthreads();

        short8 afr[2][4];
#pragma unroll
        for (int mt = 0; mt < 2; ++mt)
#pragma unroll
            for (int ks = 0; ks < 4; ++ks)
                afr[mt][ks] = *(const short8*)(Xs + (mt * 16 + l) * XSS + ks * 32 + q * 8);
        short8 bfr[2][4];
#pragma unroll
        for (int nt = 0; nt < 2; ++nt)
#pragma unroll
            for (int ks = 0; ks < 4; ++ks)
                bfr[nt][ks] = *(const short8*)(Wtb + (size_t)(w * 32 + nt * 16 + l) * DIM + ks * 32 + q * 8);

        f32x4 hc[2][2];
        hc[0][0] = hc[0][1] = hc[1][0] = hc[1][1] = (f32x4){0.f, 0.f, 0.f, 0.f};
#pragma unroll
        for (int ks = 0; ks < 4; ++ks)
#pragma unroll
            for (int mt = 0; mt < 2; ++mt)
#pragma unroll
                for (int nt = 0; nt < 2; ++nt)
                    hc[mt][nt] = __builtin_amdgcn_mfma_f32_16x16x32_bf16(
                        afr[mt][ks], bfr[nt][ks], hc[mt][nt], 0, 0, 0);

        // per-row degree scale (exact: (D·A)W == D·(AW)) + bias + relu -> Hs
#pragma unroll
        for (int nt = 0; nt < 2; ++nt) {
            float bv = bias[w * 32 + nt * 16 + l];
#pragma unroll
            for (int mt = 0; mt < 2; ++mt)
#pragma unroll
                for (int r = 0; r < 4; ++r) {
                    float s = (br == 0) ? 1.f
                            : (br == 1) ? dvv[mt][r]
                                        : dvv[mt][r] * dvv[mt][r];
                    float v = hc[mt][nt][r] * s + bv;
                    v = v > 0.f ? v : 0.f;
                    Hs[(mt * 16 + q * 4 + r) * XSS + w * 32 + nt * 16 + l] = f2bf(v);
                }
        }
        __syncthreads();

        short8 ha0 = *(const short8*)(Hs + l * XSS + w * 32 + q * 8);
        short8 ha1 = *(const short8*)(Hs + (16 + l) * XSS + w * 32 + q * 8);
        short8 wc  = *(const short8*)(Wct + (size_t)l * 384 + br * DIM + w * 32 + q * 8);
        cout0 = __builtin_amdgcn_mfma_f32_16x16x32_bf16(ha0, wc, cout0, 0, 0, 0);
        cout1 = __builtin_amdgcn_mfma_f32_16x16x32_bf16(ha1, wc, cout1, 0, 0, 0);
    }

    float* red = (float*)Xs;
#pragma unroll
    for (int r = 0; r < 4; ++r) {
        red[w * 512 + (q * 4 + r) * 16 + l]      = cout0[r];
        red[w * 512 + (16 + q * 4 + r) * 16 + l] = cout1[r];
    }
    __syncthreads();
#pragma unroll
    for (int p = t; p < 512; p += 256) {
        float s = red[p] + red[512 + p] + red[1024 + p] + red[1536 + p];
        out[(size_t)node0 * OUTD + p] = s + b_cls[p & 15];
    }
}

// ---------------- launcher ----------------
static inline size_t align256(size_t v) { return (v + 255) & ~(size_t)255; }

extern "C" void kernel_launch(void* const* d_in, const int* in_sizes, int n_in,
                              void* d_out, int out_size, void* d_ws, size_t ws_size,
                              hipStream_t stream) {
    const float* x      = (const float*)d_in[0];
    const int*   ei     = (const int*)d_in[1];
    const float* W_ego  = (const float*)d_in[2];
    const float* b_ego  = (const float*)d_in[3];
    const float* W_h1   = (const float*)d_in[4];
    const float* b_h1   = (const float*)d_in[5];
    const float* W_h2   = (const float*)d_in[6];
    const float* b_h2   = (const float*)d_in[7];
    const float* W_cls  = (const float*)d_in[8];
    const float* b_cls  = (const float*)d_in[9];
    float* out = (float*)d_out;

    const int* row = ei;
    const int* col = ei + N_EDGES;

    char* p = (char*)d_ws;
    int* deg      = (int*)p;    p += align256((size_t)N_NODES * 4);
    int* offsets  = (int*)p;    p += align256((size_t)(N_NODES + 1) * 4);
    int* cursor   = (int*)p;    p += align256((size_t)N_NODES * 4);
    int* bsum     = (int*)p;    p += align256((size_t)NB * 4);
    int* boff     = (int*)p;    p += align256((size_t)NB * 4);
    int* csr_col  = (int*)p;    p += align256((size_t)N_EDGES * 4);
    ushort* xb    = (ushort*)p; p += align256((size_t)N_NODES * DIM * 2);
    ushort* y1r   = (ushort*)p; p += align256((size_t)N_NODES * DIM * 2);
    ushort* y2r   = (ushort*)p; p += align256((size_t)N_NODES * DIM * 2);
    ushort* Wt    = (ushort*)p; p += align256((size_t)3 * DIM * DIM * 2);
    ushort* Wct   = (ushort*)p; p += align256((size_t)384 * OUTD * 2);

    hipMemsetAsync(deg, 0, (size_t)N_NODES * 4, stream);

    k_count<<<SLICES * SBPS, 256, 0, stream>>>(row, deg);
    k_convert<<<2048, 256, 0, stream>>>((const float4*)x, W_ego, W_h1, W_h2, W_cls,
                                        xb, Wt, Wct);
    k_scan1<<<NB, 256, 0, stream>>>(deg, bsum);
    k_scan2<<<1, 128, 0, stream>>>(bsum, boff, offsets);
    k_scan3<<<NB, 256, 0, stream>>>(deg, boff, offsets, cursor);
    k_scatter<<<SLICES * SBPS, 256, 0, stream>>>(row, col, cursor, csr_col);

    k_spmm<<<N_NODES / 4, 256, 0, stream>>>(xb,  y1r, offsets, csr_col);
    k_spmm<<<N_NODES / 4, 256, 0, stream>>>(y1r, y2r, offsets, csr_col);

    k_fused<<<N_NODES / 32, 256, 0, stream>>>(xb, y1r, y2r, deg, Wt, Wct,
                                              b_ego, b_h1, b_h2, b_cls, out);
}